// Round 21
// baseline (32.713 us; speedup 1.0000x reference)
//
#include <hip/hip_runtime.h>
#include <hip/hip_bf16.h>
#include <math.h>

#define N_STATIONS 276
#define CTX 384
#define TGT 96
#define BATCH 4096
#define LISTMAX 64          // max samples/station (mean 14.8, sigma 3.8 -> 13 sigma)

typedef __attribute__((ext_vector_type(8))) short bf16x8;   // 8 bf16 (4 VGPRs)
typedef __attribute__((ext_vector_type(4))) float f32x4;    // MFMA acc

__device__ __forceinline__ short f2bf(float f) {            // HW RNE cvt
    return (short)__builtin_bit_cast(unsigned short, __float2bfloat16(f));
}
// z float4-pair -> normalized bf16 A-fragment: zn = z*inv + nb
__device__ __forceinline__ bf16x8 cvt_norm(float4 a, float4 b, float inv, float nb) {
    float f[8] = {a.x, a.y, a.z, a.w, b.x, b.y, b.z, b.w};
    bf16x8 r;
#pragma unroll
    for (int i = 0; i < 8; ++i) r[i] = f2bf(fmaf(f[i], inv, nb));
    return r;
}

// ---------- single dispatch: one block (6 waves) per station ----------
// Block scans stations[] -> LDS sample list (one barrier). Wave wv computes
// cols [wv*16, wv*16+16) for all the station's 16-sample tiles: z A-frags in
// registers (once per tile), W streamed depth-2, single bf16 MFMA chain,
// fused bias/denorm/softplus epilogue. No workspace, no extra dispatches.
__global__ __launch_bounds__(384, 2) void nlinear_single(
    const float* __restrict__ z,        // (BATCH, CTX)
    const int*   __restrict__ stations, // (BATCH,)
    const float* __restrict__ W,        // (N_STATIONS, TGT, CTX)
    const float* __restrict__ bias,     // (N_STATIONS, TGT)
    const float* __restrict__ loc,
    const float* __restrict__ scale,
    float*       __restrict__ out)      // (BATCH, TGT)
{
    __shared__ int list[LISTMAX];
    __shared__ int mcnt;

    // bijective XCD swizzle over 276 = 8*34 + 4 (m204 form)
    const int b0  = blockIdx.x;
    const int xcd = b0 & 7, pos = b0 >> 3;
    const int s   = (xcd < 4 ? xcd * 35 : 140 + (xcd - 4) * 34) + pos;

    const int tid = threadIdx.x;
    if (tid == 0) mcnt = 0;
    __syncthreads();
    // cooperative scan: 11 strided passes over stations[] (16 KB, L2-broadcast)
    for (int c = tid; c < BATCH; c += 384) {
        if (stations[c] == s) {
            int p = atomicAdd(&mcnt, 1);
            if (p < LISTMAX) list[p] = c;   // within-station order irrelevant
        }
    }
    __syncthreads();
    int m = mcnt; if (m > LISTMAX) m = LISTMAX;
    if (m == 0) return;

    const int l  = tid & 63;
    const int nt = tid >> 6;            // wave = n-tile 0..5
    const int lr = l & 15;
    const int kh = (l >> 4) * 8;        // k sub-offset within K=32 step

    const float lc = loc[s], sc = scale[s];
    const float inv = 1.0f / sc, nb = -lc * inv;

    const float* wr = W + ((size_t)s * TGT + nt * 16 + lr) * CTX + kh;
    const float  bv = bias[(size_t)s * TGT + nt * 16 + lr];
    const int rbase = (l >> 4) * 4;     // D row (sample) base for this lane

    const int ntiles = (m + 15) >> 4;
    for (int tt = 0; tt < ntiles; ++tt) {
        // ---- z A-frags for this tile (loaded once; lane lr = sample) ----
        int j = tt * 16 + lr; if (j > m - 1) j = m - 1;
        const float* zr = z + (size_t)list[j] * CTX + kh;
        bf16x8 af[12];
#pragma unroll
        for (int kk = 0; kk < 12; ++kk) {
            float4 a0 = *(const float4*)(zr + kk * 32);
            float4 a1 = *(const float4*)(zr + kk * 32 + 4);
            af[kk] = cvt_norm(a0, a1, inv, nb);
        }

        // ---- W depth-2 pipeline + single bf16 MFMA chain ----
        f32x4 acc = {0.f, 0.f, 0.f, 0.f};
        float4 wc0 = *(const float4*)(wr);
        float4 wc1 = *(const float4*)(wr + 4);
#pragma unroll
        for (int kk = 0; kk < 12; ++kk) {
            float4 wn0, wn1;
            if (kk < 11) {
                wn0 = *(const float4*)(wr + (kk + 1) * 32);
                wn1 = *(const float4*)(wr + (kk + 1) * 32 + 4);
            }
            bf16x8 bh;
            bh[0] = f2bf(wc0.x); bh[1] = f2bf(wc0.y);
            bh[2] = f2bf(wc0.z); bh[3] = f2bf(wc0.w);
            bh[4] = f2bf(wc1.x); bh[5] = f2bf(wc1.y);
            bh[6] = f2bf(wc1.z); bh[7] = f2bf(wc1.w);
            acc = __builtin_amdgcn_mfma_f32_16x16x32_bf16(af[kk], bh, acc, 0, 0, 0);
            if (kk < 11) { wc0 = wn0; wc1 = wn1; }
        }

        // ---- epilogue: bias + denorm + softplus; guarded stores ----
#pragma unroll
        for (int r = 0; r < 4; ++r) {
            const int jj = tt * 16 + rbase + r;
            if (jj < m) {
                const int oid = list[jj];
                float v = (acc[r] + bv) * sc + lc;
                out[(size_t)oid * TGT + nt * 16 + lr] =
                    fmaxf(v, 0.f) + log1pf(expf(-fabsf(v)));
            }
        }
    }
}

extern "C" void kernel_launch(void* const* d_in, const int* in_sizes, int n_in,
                              void* d_out, int out_size, void* d_ws, size_t ws_size,
                              hipStream_t stream) {
    const float* z        = (const float*)d_in[0];
    const int*   stations = (const int*)  d_in[1];
    const float* W        = (const float*)d_in[2];
    const float* bias     = (const float*)d_in[3];
    const float* loc      = (const float*)d_in[4];
    const float* scale    = (const float*)d_in[5];
    float* out = (float*)d_out;

    nlinear_single<<<N_STATIONS, 384, 0, stream>>>(z, stations, W, bias, loc, scale, out);
}

// Round 22
// 30.838 us; speedup vs baseline: 1.0608x; 1.0608x over previous
//
#include <hip/hip_runtime.h>
#include <hip/hip_bf16.h>
#include <math.h>

#define N_STATIONS 276
#define CTX 384
#define TGT 96
#define BATCH 4096
#define NT_MAX 532                  // >= Σceil(m/16) worst case
#define NTASK (NT_MAX * 6)          // 3192 = 8*399
#define CPX (NTASK / 8)             // 399 (bijective XCD swizzle)

// ws layout (ints):
//   [0]                 ntiles
//   [1 .. 533)          tiles packed s<<16|tt
//   [1024 .. 5120)      order
//   [5120 .. 5397)      offsets
//   [8192 .. 8192+532*32)  per-tile meta: {s, mrem, oids[16], pad...} (32 ints)
//   [262144 .. )        zf: per-tile A-fragment buffer, 12 KB each (bf16)
#define META_OFF 8192
#define ZF_OFF   262144             // int offset = 1 MB byte offset

typedef __attribute__((ext_vector_type(8))) short bf16x8;   // 8 bf16 (4 VGPRs)
typedef __attribute__((ext_vector_type(4))) float f32x4;    // MFMA acc

__device__ __forceinline__ short f2bf(float f) {
    return (short)__builtin_bit_cast(unsigned short, __float2bfloat16(f));
}

// ---------- kernel 1: per-station lists + 16-sample tile list ----------
__global__ __launch_bounds__(1024) void build_lists(
    const int* __restrict__ stations, int* __restrict__ ws)
{
    __shared__ int cnt[N_STATIONS], cnt2[N_STATIONS];
    __shared__ int poff[N_STATIONS + 1], tpoff[N_STATIONS + 1];
    const int tid = threadIdx.x;
    for (int i = tid; i < N_STATIONS; i += 1024) { cnt[i] = 0; cnt2[i] = 0; }
    __syncthreads();
    for (int b = tid; b < BATCH; b += 1024) atomicAdd(&cnt[stations[b]], 1);
    __syncthreads();
    if (tid < 64) {   // dual wave-parallel inclusive scan (samples, tiles)
        int run = 0, trun = 0;
        for (int base = 0; base < N_STATIONS; base += 64) {
            const int i = base + tid;
            int c  = (i < N_STATIONS) ? cnt[i] : 0;
            int v  = c, tv = (c + 15) >> 4;
#pragma unroll
            for (int off = 1; off < 64; off <<= 1) {
                int u  = __shfl_up(v, off, 64);
                int tu = __shfl_up(tv, off, 64);
                if (tid >= off) { v += u; tv += tu; }
            }
            if (i < N_STATIONS) { poff[i + 1] = run + v; tpoff[i + 1] = trun + tv; }
            run  += __shfl(v, 63, 64);
            trun += __shfl(tv, 63, 64);
        }
        if (tid == 0) { poff[0] = 0; tpoff[0] = 0; }
    }
    __syncthreads();
    int* order = ws + 1024;
    for (int b = tid; b < BATCH; b += 1024) {
        int s = stations[b];
        int p = atomicAdd(&cnt2[s], 1);
        order[poff[s] + p] = b;          // within-station order irrelevant to outputs
    }
    for (int i = tid; i < N_STATIONS; i += 1024) {
        int n = (cnt[i] + 15) >> 4, base = tpoff[i];
        for (int t = 0; t < n; ++t) ws[1 + base + t] = (i << 16) | t;
    }
    if (tid <= N_STATIONS) ws[5120 + tid] = poff[tid];
    if (tid == 0) ws[0] = tpoff[N_STATIONS];
}

// ---------- kernel 2: z-staging — gather+normalize+bf16 into A-frag layout ----------
// One block per tile. zf item q (16B) = lane (q&63) of K-step (q>>6):
// sample = lane&15, k = kstep*32 + (lane>>4)*8 .. +8. Also writes meta record.
__global__ __launch_bounds__(256) void zstage(
    const float* __restrict__ z,
    const float* __restrict__ loc,
    const float* __restrict__ scale,
    int* __restrict__ ws)
{
    const int ntiles = ws[0];
    const int tb = blockIdx.x;
    if (tb >= ntiles) return;

    const int pk = ws[1 + tb];
    const int s  = pk >> 16;
    const int tt = pk & 0xFFFF;
    const int* order   = ws + 1024;
    const int* offsets = ws + 5120;
    const int start = offsets[s];
    const int m     = offsets[s + 1] - start;

    const float lc = loc[s], inv = 1.0f / scale[s], nb = -lc * inv;

    int* rec = ws + META_OFF + tb * 32;
    const int t = threadIdx.x;
    if (t < 16) {
        int j = tt * 16 + t; if (j > m - 1) j = m - 1;
        rec[2 + t] = order[start + j];
    }
    if (t == 0) { rec[0] = s; int mr = m - tt * 16; rec[1] = mr > 16 ? 16 : mr; }

    unsigned short* zt = (unsigned short*)(ws + ZF_OFF) + (size_t)tb * 6144;
    for (int q = t; q < 768; q += 256) {
        const int kstep = q >> 6, lane = q & 63;
        const int sample = lane & 15;
        const int kb = kstep * 32 + (lane >> 4) * 8;
        int j = tt * 16 + sample; if (j > m - 1) j = m - 1;
        const float* zr = z + (size_t)order[start + j] * CTX + kb;
        float4 a0 = *(const float4*)zr;
        float4 a1 = *(const float4*)(zr + 4);
        float f[8] = {a0.x, a0.y, a0.z, a0.w, a1.x, a1.y, a1.z, a1.w};
        union { unsigned short u[8]; uint4 v; } o;
#pragma unroll
        for (int i = 0; i < 8; ++i)
            o.u[i] = (unsigned short)f2bf(fmaf(f[i], inv, nb));
        *(uint4*)(zt + (size_t)q * 8) = o.v;
    }
}

// ---------- kernel 3: hot — one wave per (tile, n-tile); 12 x {W-cvt, MFMA} ----------
// No indirection (meta record), no z cvt (staged), single bf16 MFMA chain.
__global__ __launch_bounds__(64, 4) void nlinear_hot(
    const float* __restrict__ W,        // (N_STATIONS, TGT, CTX)
    const float* __restrict__ bias,     // (N_STATIONS, TGT)
    const float* __restrict__ loc,
    const float* __restrict__ scale,
    const int*   __restrict__ ws,
    float*       __restrict__ out)      // (BATCH, TGT)
{
    const int ntasks = ws[0] * 6;
    const int b0 = blockIdx.x;
    const int b  = (b0 & 7) * CPX + (b0 >> 3);   // bijective XCD swizzle
    if (b >= ntasks) return;

    const int tile = b / 6;
    const int nt   = b - tile * 6;

    const int* rec = ws + META_OFF + tile * 32;
    const int s    = rec[0];
    const int mrem = rec[1];

    const int l  = threadIdx.x;         // 0..63
    const int lr = l & 15;
    const int kh = (l >> 4) * 8;

    const float* wr = W + ((size_t)s * TGT + nt * 16 + lr) * CTX + kh;
    const unsigned short* zt = (const unsigned short*)(ws + ZF_OFF) + (size_t)tile * 6144;

    // depth-2 software pipeline over 12 K-steps
    f32x4 acc = {0.f, 0.f, 0.f, 0.f};
    float4 wc0 = *(const float4*)(wr);
    float4 wc1 = *(const float4*)(wr + 4);
    bf16x8 za  = *(const bf16x8*)(zt + (size_t)l * 8);

#pragma unroll
    for (int kk = 0; kk < 12; ++kk) {
        float4 wn0, wn1; bf16x8 zn_;
        if (kk < 11) {
            wn0 = *(const float4*)(wr + (kk + 1) * 32);
            wn1 = *(const float4*)(wr + (kk + 1) * 32 + 4);
            zn_ = *(const bf16x8*)(zt + ((size_t)(kk + 1) * 64 + l) * 8);
        }
        bf16x8 bh;
        bh[0] = f2bf(wc0.x); bh[1] = f2bf(wc0.y);
        bh[2] = f2bf(wc0.z); bh[3] = f2bf(wc0.w);
        bh[4] = f2bf(wc1.x); bh[5] = f2bf(wc1.y);
        bh[6] = f2bf(wc1.z); bh[7] = f2bf(wc1.w);
        acc = __builtin_amdgcn_mfma_f32_16x16x32_bf16(za, bh, acc, 0, 0, 0);
        if (kk < 11) { wc0 = wn0; wc1 = wn1; za = zn_; }
    }

    // epilogue: bias + denorm + softplus; D row=(l>>4)*4+r (sample), col=lr
    const float sc = scale[s], lc = loc[s];
    const float bv = bias[(size_t)s * TGT + nt * 16 + lr];
    const int rbase = (l >> 4) * 4;
#pragma unroll
    for (int r = 0; r < 4; ++r) {
        const int jj = rbase + r;
        if (jj < mrem) {
            const int oid = rec[2 + jj];
            float v = (acc[r] + bv) * sc + lc;
            out[(size_t)oid * TGT + nt * 16 + lr] =
                fmaxf(v, 0.f) + log1pf(expf(-fabsf(v)));
        }
    }
}

extern "C" void kernel_launch(void* const* d_in, const int* in_sizes, int n_in,
                              void* d_out, int out_size, void* d_ws, size_t ws_size,
                              hipStream_t stream) {
    const float* z        = (const float*)d_in[0];
    const int*   stations = (const int*)  d_in[1];
    const float* W        = (const float*)d_in[2];
    const float* bias     = (const float*)d_in[3];
    const float* loc      = (const float*)d_in[4];
    const float* scale    = (const float*)d_in[5];
    float* out = (float*)d_out;
    int* ws = (int*)d_ws;

    build_lists<<<1, 1024, 0, stream>>>(stations, ws);
    zstage<<<NT_MAX, 256, 0, stream>>>(z, loc, scale, ws);
    nlinear_hot<<<NTASK, 64, 0, stream>>>(W, bias, loc, scale, ws, out);
}